// Round 1
// 444.991 us; speedup vs baseline: 2.6667x; 2.6667x over previous
//
#include <hip/hip_runtime.h>

// Soft-DTW, B=64, L=1024, C=64, gamma=1.
// Structure: per batch, 16 row-bands of 64 rows; wave = band; each wave does ONE
// continuous skewed sweep over all 1024 columns (lane r handles row band+r, col c
// at local step c+r). Waves pipeline self-timed: per-64-col chunk flags.
// 2 blocks per batch (8 waves each, 512 thr), 128 blocks total; cross-block
// boundary (band 7 -> 8) via global memory + agent-scope release/acquire flag.
// DP runs in base-2 domain (D pre-scaled by 1/ln2, v_exp/v_log native, out * ln2).

typedef unsigned short ushort_t;
typedef __attribute__((ext_vector_type(8))) short short8;
typedef __attribute__((ext_vector_type(4))) float f32x4;
typedef __attribute__((ext_vector_type(4))) unsigned short ushort4v;

constexpr int B_ = 64, L_ = 1024, C_ = 64;

#define BIGV 1e10f
#define INV_LN2 1.44269504088896340736f
#define LN2F 0.69314718055994530942f

static __device__ __forceinline__ ushort_t f2bf(float f) {
  unsigned u = __builtin_bit_cast(unsigned, f);
  unsigned r = (u + 0x7fffu + ((u >> 16) & 1u)) >> 16;
  return (ushort_t)r;
}
static __device__ __forceinline__ float exp2_(float x) {
  float r; asm("v_exp_f32 %0, %1" : "=v"(r) : "v"(x)); return r;
}
static __device__ __forceinline__ float log2_(float x) {
  float r; asm("v_log_f32 %0, %1" : "=v"(r) : "v"(x)); return r;
}
static __device__ __forceinline__ unsigned cvt_pk_bf16(float lo, float hi) {
  unsigned r; asm("v_cvt_pk_bf16_f32 %0, %1, %2" : "=v"(r) : "v"(lo), "v"(hi)); return r;
}

// Pass 1: bf16 conversion (RNE, same as before), squared norms pre-scaled by 1/ln2,
// and zero the cross-block flags. Vectorized: float4 loads, 4 rows/wave/iter.
__global__ __launch_bounds__(256) void prep_kernel(
    const float* __restrict__ x, const float* __restrict__ y,
    ushort_t* __restrict__ xb, ushort_t* __restrict__ yb,
    float* __restrict__ x2, float* __restrict__ y2, int* __restrict__ flagsG)
{
  if (blockIdx.x == 0 && threadIdx.x < B_) flagsG[threadIdx.x] = 0;
  const int lane = threadIdx.x & 63;
  const int sub = lane >> 4;          // row within group of 4
  const int cg  = lane & 15;          // 4-float column group
  const int wv = (blockIdx.x * blockDim.x + threadIdx.x) >> 6;
  const int nw = (gridDim.x * blockDim.x) >> 6;
  const int totalGroups = (2 * B_ * L_) >> 2;
  for (int g = wv; g < totalGroups; g += nw) {
    int r = g * 4 + sub;
    const float* src; ushort_t* dst; float* nrm;
    if (r < B_ * L_) { src = x; dst = xb; nrm = x2; }
    else             { r -= B_ * L_; src = y; dst = yb; nrm = y2; }
    const float4 v = *(const float4*)(src + (size_t)r * C_ + cg * 4);
    ushort4v p;
    p.x = f2bf(v.x); p.y = f2bf(v.y); p.z = f2bf(v.z); p.w = f2bf(v.w);
    *(ushort4v*)(dst + (size_t)r * C_ + cg * 4) = p;
    float s = v.x*v.x + v.y*v.y + v.z*v.z + v.w*v.w;
    s += __shfl_xor(s, 1); s += __shfl_xor(s, 2);
    s += __shfl_xor(s, 4); s += __shfl_xor(s, 8);
    if (cg == 0) nrm[r] = s * INV_LN2;      // pre-scaled into base-2 domain
  }
}

// HSRC: 0 = top boundary is BIG (band 0), 1 = LDS Hb row, 2 = global HX (readlane)
// HDST: 0 = write bottom row to LDS Hb, 1 = write to global HX, 2 = none (last band)
// GATED: boundary handling + validity gating (only first chunk and tail need it)
template<int HSRC, int HDST, bool GATED>
static __device__ __forceinline__ void dp_steps(
    int nsteps, int cbase, int lane,
    float& cur, float& up_prev, float& hv_last,
    const ushort_t* __restrict__ dtrow, const float* __restrict__ HbSrc,
    float* __restrict__ HbDst, float* __restrict__ HX,
    int bpa, float zsel, int hst)
{
  int c = cbase - lane;
  #pragma unroll 4
  for (int u = 0; u < nsteps; ++u, ++c) {
    float upn = __builtin_bit_cast(float,
        __builtin_amdgcn_ds_bpermute(bpa, __builtin_bit_cast(int, cur)));
    float hv;
    if constexpr (HSRC == 0)      hv = BIGV;
    else if constexpr (HSRC == 1) hv = HbSrc[c & 1023];
    else                          hv = __builtin_bit_cast(float, __builtin_amdgcn_readlane(hst, u));
    float dv = __builtin_bit_cast(float, ((unsigned)dtrow[c & 127]) << 16);
    float up = (lane == 0) ? hv : upn;
    float dg = (lane == 0) ? hv_last : up_prev;   // = last step's shfl result
    float lf = cur;
    if constexpr (GATED) {
      if (c == 0) { dg = zsel; lf = BIGV; }       // left/corner boundary
    }
    float mn = fminf(fminf(up, dg), lf);
    float e = exp2_(mn - up) + exp2_(mn - dg) + exp2_(mn - lf);
    float nv = (dv + mn) - log2_(e);
    up_prev = upn;
    hv_last = hv;
    bool ok = GATED ? (((unsigned)c) < 1024u) : true;
    if (ok) {
      cur = nv;
      if (lane == 63) {
        if constexpr (HDST == 0)      HbDst[c] = nv;
        else if constexpr (HDST == 1) HX[c] = nv;
      }
    }
  }
}

template<int HSRC, int HDST>
static __device__ __forceinline__ void run_band(
    const ushort_t* __restrict__ xbB, const ushort_t* __restrict__ ybB,
    const float* __restrict__ x2B, const float* __restrict__ y2B,
    float* __restrict__ HX, int* __restrict__ flagG,
    ushort_t* __restrict__ Dtw, const float* __restrict__ HbSrc,
    float* __restrict__ HbDst, int* __restrict__ cin, int* __restrict__ cout,
    int lane, int W, float* __restrict__ outp)
{
  const int m = lane & 15, q = lane >> 4;
  const int i0 = W * 64;

  // x fragments + x2 rows: fixed for the whole band (hoisted out of the sweep)
  short8 af[4][2];
  #pragma unroll
  for (int mt = 0; mt < 4; ++mt) {
    #pragma unroll
    for (int ks = 0; ks < 2; ++ks)
      af[mt][ks] = *(const short8*)(xbB + (size_t)(i0 + mt * 16 + m) * C_ + ks * 32 + q * 8);
  }
  f32x4 x2q[4];
  #pragma unroll
  for (int mt = 0; mt < 4; ++mt) x2q[mt] = *(const f32x4*)(x2B + i0 + mt * 16 + q * 4);

  // y fragments: single buffer, prefetched one chunk ahead of consumption
  short8 bfr0[4], bfr1[4];
  auto load_bfr = [&](int tc) {
    const ushort_t* yb0 = ybB + (size_t)tc * 64 * C_;
    #pragma unroll
    for (int nt = 0; nt < 4; ++nt) {
      bfr0[nt] = *(const short8*)(yb0 + (size_t)(nt * 16 + m) * C_ + q * 8);
      bfr1[nt] = *(const short8*)(yb0 + (size_t)(nt * 16 + m) * C_ + 32 + q * 8);
    }
  };
  // Gram tile for chunk tc -> Dt columns (tc*64 & 127) .. +63, bf16, base-2 scaled
  auto gram = [&](int tc) {
    const int cb = (tc * 64) & 127;
    const float* y2j = y2B + tc * 64;
    ushort_t* dbase = Dtw + cb + m;
    #pragma unroll
    for (int mt = 0; mt < 4; ++mt) {
      #pragma unroll
      for (int nt = 0; nt < 4; ++nt) {
        f32x4 acc = {0.f, 0.f, 0.f, 0.f};
        acc = __builtin_amdgcn_mfma_f32_16x16x32_bf16(af[mt][0], bfr0[nt], acc, 0, 0, 0);
        acc = __builtin_amdgcn_mfma_f32_16x16x32_bf16(af[mt][1], bfr1[nt], acc, 0, 0, 0);
        float y2v = y2j[nt * 16 + m];
        float d0 = fmaf(acc[0], -2.f * INV_LN2, x2q[mt][0] + y2v);
        float d1 = fmaf(acc[1], -2.f * INV_LN2, x2q[mt][1] + y2v);
        float d2 = fmaf(acc[2], -2.f * INV_LN2, x2q[mt][2] + y2v);
        float d3 = fmaf(acc[3], -2.f * INV_LN2, x2q[mt][3] + y2v);
        unsigned p01 = cvt_pk_bf16(d0, d1);
        unsigned p23 = cvt_pk_bf16(d2, d3);
        ushort_t* wp = dbase + (mt * 16 + q * 4) * 128 + nt * 16;
        wp[0]   = (ushort_t)p01;
        wp[128] = (ushort_t)(p01 >> 16);
        wp[256] = (ushort_t)p23;
        wp[384] = (ushort_t)(p23 >> 16);
      }
    }
  };

  // DP state
  float cur = 0.f, up_prev = BIGV, hv_last = BIGV;
  const float zsel = (W == 0 && lane == 0) ? 0.f : BIGV;  // R[-1][-1]=0 only at origin
  const int bpa = (lane ? lane - 1 : 0) << 2;
  const ushort_t* dtrow = Dtw + lane * 128;

  load_bfr(0);
  gram(0);

  for (int t = 0; t < 16; ++t) {
    if (t < 15) load_bfr(t + 1);          // hide HBM latency under the 64 DP steps
    int hst = 0;
    if constexpr (HSRC == 1) {
      int k = 0;
      while (__hip_atomic_load(cin, __ATOMIC_ACQUIRE, __HIP_MEMORY_SCOPE_WORKGROUP) < t + 1) {
        __builtin_amdgcn_s_sleep(1);
        if (++k > (1 << 27)) break;       // bounded: garbage instead of hang
      }
    } else if constexpr (HSRC == 2) {
      int k = 0;
      while (__hip_atomic_load(flagG, __ATOMIC_ACQUIRE, __HIP_MEMORY_SCOPE_AGENT) < t + 1) {
        __builtin_amdgcn_s_sleep(8);
        if (++k > (1 << 27)) break;
      }
      hst = __builtin_bit_cast(int, HX[t * 64 + lane]);
    }
    if (t == 0)
      dp_steps<HSRC, HDST, true >(64, 0,      lane, cur, up_prev, hv_last, dtrow, HbSrc, HbDst, HX, bpa, zsel, hst);
    else
      dp_steps<HSRC, HDST, false>(64, t * 64, lane, cur, up_prev, hv_last, dtrow, HbSrc, HbDst, HX, bpa, zsel, hst);
    // signal: after iter t, bottom-row cols <= 64t are written
    if constexpr (HDST == 0) {
      if (lane == 0) __hip_atomic_store(cout, t, __ATOMIC_RELEASE, __HIP_MEMORY_SCOPE_WORKGROUP);
    } else if constexpr (HDST == 1) {
      if (lane == 0) __hip_atomic_store(flagG, t, __ATOMIC_RELEASE, __HIP_MEMORY_SCOPE_AGENT);
    }
    if (t < 15) gram(t + 1);              // write into the slot just drained
  }
  // tail: 63 steps to finish the skew (cols up to 1023 for high lanes)
  dp_steps<0, HDST, true>(63, 1024, lane, cur, up_prev, hv_last, dtrow, HbSrc, HbDst, HX, bpa, zsel, 0);
  if constexpr (HDST == 0) {
    if (lane == 0) __hip_atomic_store(cout, 16, __ATOMIC_RELEASE, __HIP_MEMORY_SCOPE_WORKGROUP);
  } else if constexpr (HDST == 1) {
    if (lane == 0) __hip_atomic_store(flagG, 16, __ATOMIC_RELEASE, __HIP_MEMORY_SCOPE_AGENT);
  }
  if (W == 15 && lane == 63) *outp = cur * LN2F;  // back to natural-log domain
}

__global__ __launch_bounds__(512) void sdtw_kernel(
    const ushort_t* __restrict__ xb, const ushort_t* __restrict__ yb,
    const float* __restrict__ x2g, const float* __restrict__ y2g,
    float* __restrict__ HXg, int* __restrict__ flagsG,
    float* __restrict__ out)
{
  // LDS: 8*64*128*2 = 131072 (Dt, 2-chunk ring per wave) + 7*1024*4 = 28672 (Hb)
  //      + 32 (flags) = 159776 <= 163840
  __shared__ ushort_t Dt[8][64][128];
  __shared__ float Hb[7][1024];
  __shared__ int cflag[8];

  const int b = blockIdx.x & 63;        // pair (b, b+64) lands on same XCD (rr mod 8)
  const int half = blockIdx.x >> 6;     // 0: bands 0-7, 1: bands 8-15
  const int w = threadIdx.x >> 6;
  const int lane = threadIdx.x & 63;
  const int W = half * 8 + w;

  if (threadIdx.x < 8) cflag[threadIdx.x] = 0;
  __syncthreads();                      // only barrier in the kernel

  const ushort_t* xbB = xb + (size_t)b * L_ * C_;
  const ushort_t* ybB = yb + (size_t)b * L_ * C_;
  const float* x2B = x2g + b * L_;
  const float* y2B = y2g + b * L_;
  float* HX = HXg + (size_t)b * L_;
  int* fG = flagsG + b;
  ushort_t* Dtw = &Dt[w][0][0];
  const float* HbSrc = (w > 0) ? &Hb[w - 1][0] : &Hb[0][0];
  float* HbDst = (w < 7) ? &Hb[w][0] : &Hb[0][0];
  int* cin  = (w > 0) ? &cflag[w - 1] : &cflag[0];
  int* cout = (w < 7) ? &cflag[w] : &cflag[7];
  float* outp = out + b;

  if (half == 0) {
    if (w == 0)
      run_band<0, 0>(xbB, ybB, x2B, y2B, HX, fG, Dtw, HbSrc, HbDst, cin, cout, lane, W, outp);
    else if (w < 7)
      run_band<1, 0>(xbB, ybB, x2B, y2B, HX, fG, Dtw, HbSrc, HbDst, cin, cout, lane, W, outp);
    else
      run_band<1, 1>(xbB, ybB, x2B, y2B, HX, fG, Dtw, HbSrc, HbDst, cin, cout, lane, W, outp);
  } else {
    if (w == 0)
      run_band<2, 0>(xbB, ybB, x2B, y2B, HX, fG, Dtw, HbSrc, HbDst, cin, cout, lane, W, outp);
    else if (w < 7)
      run_band<1, 0>(xbB, ybB, x2B, y2B, HX, fG, Dtw, HbSrc, HbDst, cin, cout, lane, W, outp);
    else
      run_band<1, 2>(xbB, ybB, x2B, y2B, HX, fG, Dtw, HbSrc, HbDst, cin, cout, lane, W, outp);
  }
}

extern "C" void kernel_launch(void* const* d_in, const int* in_sizes, int n_in,
                              void* d_out, int out_size, void* d_ws, size_t ws_size,
                              hipStream_t stream) {
  const float* x = (const float*)d_in[0];
  const float* y = (const float*)d_in[1];
  float* out = (float*)d_out;

  // ws: xb 8MB | yb 8MB | x2 256KB | y2 256KB | HX 256KB | flagsG 256B
  char* ws = (char*)d_ws;
  const size_t XB = (size_t)B_ * L_ * C_ * 2;   // 8 MB
  const size_t NB = (size_t)B_ * L_ * 4;        // 256 KB
  ushort_t* xb = (ushort_t*)ws;
  ushort_t* yb = (ushort_t*)(ws + XB);
  float* x2 = (float*)(ws + 2 * XB);
  float* y2 = (float*)(ws + 2 * XB + NB);
  float* HX = (float*)(ws + 2 * XB + 2 * NB);
  int* flagsG = (int*)(ws + 2 * XB + 3 * NB);

  prep_kernel<<<512, 256, 0, stream>>>(x, y, xb, yb, x2, y2, flagsG);
  sdtw_kernel<<<128, 512, 0, stream>>>(xb, yb, x2, y2, HX, flagsG, out);
}

// Round 2
// 355.320 us; speedup vs baseline: 3.3397x; 1.2524x over previous
//
#include <hip/hip_runtime.h>

// Soft-DTW, B=64, L=1024, C=64, gamma=1.
// 16 row-bands of 64 rows per batch; wave = band; lane = row within band.
// One continuous skewed sweep per wave (lane r, col c at local step c+r).
// 4 waves/block, 4 blocks/batch (256 blocks on 256 CUs, 1 wave/SIMD).
// Per-step recurrence is pure VALU: up-shift via DPP wave_shr:1, top-boundary
// values rotated in via DPP wave_shl:1, D row preloaded from skewed LDS.
// Band handoff: LDS Hb + flags inside a block; global HX + agent flags across.
// DP in base-2 domain (D pre-scaled by 1/ln2, v_exp/v_log native, out * ln2).

typedef unsigned short ushort_t;
typedef __attribute__((ext_vector_type(8))) short short8;
typedef __attribute__((ext_vector_type(4))) float f32x4;
typedef __attribute__((ext_vector_type(4))) unsigned short ushort4v;

constexpr int B_ = 64, L_ = 1024, C_ = 64;
constexpr int DSTR = 130;            // u16 row stride: 128-slot ring + 2 pad
constexpr int HBSTR = 1280;          // Hb row stride (pads LDS >80KB -> 1 block/CU)

#define BIGV 1e10f
#define INV_LN2 1.44269504088896340736f
#define LN2F 0.69314718055994530942f
#define DPP_WAVE_SHL1 0x130
#define DPP_WAVE_SHR1 0x138

static __device__ __forceinline__ ushort_t f2bf(float f) {
  unsigned u = __builtin_bit_cast(unsigned, f);
  unsigned r = (u + 0x7fffu + ((u >> 16) & 1u)) >> 16;
  return (ushort_t)r;
}
static __device__ __forceinline__ float exp2_(float x) {
  float r; asm("v_exp_f32 %0, %1" : "=v"(r) : "v"(x)); return r;
}
static __device__ __forceinline__ float log2_(float x) {
  float r; asm("v_log_f32 %0, %1" : "=v"(r) : "v"(x)); return r;
}
static __device__ __forceinline__ unsigned cvt_pk_bf16(float lo, float hi) {
  unsigned r; asm("v_cvt_pk_bf16_f32 %0, %1, %2" : "=v"(r) : "v"(lo), "v"(hi)); return r;
}
// up-shift across the wave: lane i <- lane i-1; lane 0 <- old's lane 0
static __device__ __forceinline__ float dpp_shr1(float old, float src) {
  return __builtin_bit_cast(float, __builtin_amdgcn_update_dpp(
      __builtin_bit_cast(int, old), __builtin_bit_cast(int, src),
      DPP_WAVE_SHR1, 0xF, 0xF, false));
}
// rotate-down: lane i <- lane i+1 (lane 63 keeps old)
static __device__ __forceinline__ float dpp_shl1(float v) {
  return __builtin_bit_cast(float, __builtin_amdgcn_update_dpp(
      __builtin_bit_cast(int, v), __builtin_bit_cast(int, v),
      DPP_WAVE_SHL1, 0xF, 0xF, false));
}

// Pass 1: bf16 conversion (RNE), squared norms pre-scaled by 1/ln2, zero flags.
__global__ __launch_bounds__(256) void prep_kernel(
    const float* __restrict__ x, const float* __restrict__ y,
    ushort_t* __restrict__ xb, ushort_t* __restrict__ yb,
    float* __restrict__ x2, float* __restrict__ y2, int* __restrict__ flagsG)
{
  if (blockIdx.x == 0 && threadIdx.x < 192) flagsG[threadIdx.x] = 0;
  const int lane = threadIdx.x & 63;
  const int sub = lane >> 4;
  const int cg  = lane & 15;
  const int wv = (blockIdx.x * blockDim.x + threadIdx.x) >> 6;
  const int nw = (gridDim.x * blockDim.x) >> 6;
  const int totalGroups = (2 * B_ * L_) >> 2;
  for (int g = wv; g < totalGroups; g += nw) {
    int r = g * 4 + sub;
    const float* src; ushort_t* dst; float* nrm;
    if (r < B_ * L_) { src = x; dst = xb; nrm = x2; }
    else             { r -= B_ * L_; src = y; dst = yb; nrm = y2; }
    const float4 v = *(const float4*)(src + (size_t)r * C_ + cg * 4);
    ushort4v p;
    p.x = f2bf(v.x); p.y = f2bf(v.y); p.z = f2bf(v.z); p.w = f2bf(v.w);
    *(ushort4v*)(dst + (size_t)r * C_ + cg * 4) = p;
    float s = v.x*v.x + v.y*v.y + v.z*v.z + v.w*v.w;
    s += __shfl_xor(s, 1); s += __shfl_xor(s, 2);
    s += __shfl_xor(s, 4); s += __shfl_xor(s, 8);
    if (cg == 0) nrm[r] = s * INV_LN2;
  }
}

// One 64-step chunk. HDST: 0 = LDS Hb, 1 = global HX, 2 = none.
// FIRST: chunk 0 (left-boundary gating).
template<int HDST, bool FIRST>
static __device__ __forceinline__ void dp_chunk(
    const int t, const int lane, float& cur, float& dgp, float hvv,
    const float zsel, const ushort_t* __restrict__ DtwLane,
    float* __restrict__ HbDst, float* __restrict__ HXB)
{
  const unsigned* pw = (const unsigned*)(DtwLane + ((t << 6) & 127));
  const int cb = (t << 6) - 63;        // lane-63 col for local step u is cb+u
  unsigned a0 = pw[0], a1 = pw[1], b0 = pw[2], b1 = pw[3];

  auto step = [&](unsigned dw, int k, int u) -> float {
    float dv = __builtin_bit_cast(float, (k & 1) ? (dw & 0xffff0000u) : (dw << 16));
    float up = dpp_shr1(hvv, cur);     // lane0 <- hvv[0] = top row value
    float dg = dgp, lf = cur;
    if constexpr (FIRST) {
      bool at0 = (u == lane);          // c == 0: left boundary
      dg = at0 ? zsel : dg;
      lf = at0 ? BIGV : lf;
    }
    float mn = fminf(fminf(up, dg), lf);
    float e = exp2_(mn - up) + exp2_(mn - dg) + exp2_(mn - lf);
    float nv = (dv + mn) - log2_(e);
    dgp = up;
    hvv = dpp_shl1(hvv);               // advance top-row value toward lane 0
    if constexpr (FIRST) { if (u >= lane) cur = nv; }
    else cur = nv;
    return nv;
  };
  auto flush4 = [&](int c0, float v0, float v1, float v2, float v3) {
    if constexpr (HDST == 0) {
      if (lane == 63) { HbDst[c0] = v0; HbDst[c0+1] = v1; HbDst[c0+2] = v2; HbDst[c0+3] = v3; }
    } else if constexpr (HDST == 1) {
      if (lane == 63) { HXB[c0] = v0; HXB[c0+1] = v1; HXB[c0+2] = v2; HXB[c0+3] = v3; }
    }
  };

  #pragma unroll 1
  for (int g = 0; g < 8; ++g) {
    const int u0 = g * 8;
    unsigned n0 = 0, n1 = 0, n2 = 0, n3 = 0;
    if (g < 7) {
      n0 = pw[u0/2 + 4]; n1 = pw[u0/2 + 5]; n2 = pw[u0/2 + 6]; n3 = pw[u0/2 + 7];
    }
    float v0 = step(a0, 0, u0 + 0);
    float v1 = step(a0, 1, u0 + 1);
    float v2 = step(a1, 0, u0 + 2);
    float v3 = step(a1, 1, u0 + 3);
    if constexpr (!FIRST) flush4(cb + u0, v0, v1, v2, v3);
    float v4 = step(b0, 0, u0 + 4);
    float v5 = step(b0, 1, u0 + 5);
    float v6 = step(b1, 0, u0 + 6);
    float v7 = step(b1, 1, u0 + 7);
    if constexpr (!FIRST) flush4(cb + u0 + 4, v4, v5, v6, v7);
    a0 = n0; a1 = n1; b0 = n2; b1 = n3;
    (void)v0; (void)v1; (void)v2; (void)v3; (void)v4; (void)v5; (void)v6; (void)v7;
  }
  if constexpr (FIRST) {
    // chunk 0: lane 63's only valid col is 0 (reached at u=63, value in cur)
    if constexpr (HDST == 0) { if (lane == 63) HbDst[0] = cur; }
    else if constexpr (HDST == 1) { if (lane == 63) HXB[0] = cur; }
  }
}

// Tail: 63 skew-drain steps, c = 1024 + u - lane, valid iff u < lane.
template<int HDST>
static __device__ __forceinline__ void dp_tail(
    const int lane, float& cur, float& dgp,
    const ushort_t* __restrict__ DtwLane,
    float* __restrict__ HbDst, float* __restrict__ HXB)
{
  const unsigned* pw = (const unsigned*)(DtwLane);   // slots 0..63 ((1024)&127==0)
  #pragma unroll 1
  for (int g = 0; g < 8; ++g) {
    unsigned w0 = pw[g*4], w1 = pw[g*4+1], w2 = pw[g*4+2], w3 = pw[g*4+3];
    #pragma unroll
    for (int k = 0; k < 8; ++k) {
      const int u = g * 8 + k;
      unsigned dw = (k < 2) ? w0 : (k < 4) ? w1 : (k < 6) ? w2 : w3;
      float dv = __builtin_bit_cast(float, (k & 1) ? (dw & 0xffff0000u) : (dw << 16));
      float up = dpp_shr1(BIGV, cur);
      float dg = dgp, lf = cur;
      float mn = fminf(fminf(up, dg), lf);
      float e = exp2_(mn - up) + exp2_(mn - dg) + exp2_(mn - lf);
      float nv = (dv + mn) - log2_(e);
      dgp = up;
      if (u < lane) {
        cur = nv;
        if constexpr (HDST == 0) { if (lane == 63) HbDst[961 + u] = nv; }
        else if constexpr (HDST == 1) { if (lane == 63) HXB[961 + u] = nv; }
      }
    }
  }
}

static __device__ __forceinline__ void spin_lds(int* f, int v) {
  int k = 0;
  while (__hip_atomic_load(f, __ATOMIC_ACQUIRE, __HIP_MEMORY_SCOPE_WORKGROUP) < v) {
    __builtin_amdgcn_s_sleep(1);
    if (++k > (1 << 26)) break;
  }
}
static __device__ __forceinline__ void spin_glb(int* f, int v) {
  int k = 0;
  while (__hip_atomic_load(f, __ATOMIC_ACQUIRE, __HIP_MEMORY_SCOPE_AGENT) < v) {
    __builtin_amdgcn_s_sleep(8);
    if (++k > (1 << 26)) break;
  }
}

// HSRC: 0 = BIG top boundary (band 0), 1 = LDS Hb, 2 = global HX.
// HDST: 0 = LDS Hb, 1 = global HX, 2 = none (band 15).
template<int HSRC, int HDST>
static __device__ __forceinline__ void run_band(
    const ushort_t* __restrict__ xbB, const ushort_t* __restrict__ ybB,
    const float* __restrict__ x2B, const float* __restrict__ y2B,
    const float* __restrict__ HXin, float* __restrict__ HXout,
    int* __restrict__ fGin, int* __restrict__ fGout,
    ushort_t* __restrict__ Dtw, const float* __restrict__ HbSrc,
    float* __restrict__ HbDst, int* __restrict__ cin, int* __restrict__ cout,
    const int lane, const int W, float* __restrict__ outp)
{
  const int m = lane & 15, q = lane >> 4;
  const int i0 = W * 64;

  short8 af[4][2];
  #pragma unroll
  for (int mt = 0; mt < 4; ++mt)
    #pragma unroll
    for (int ks = 0; ks < 2; ++ks)
      af[mt][ks] = *(const short8*)(xbB + (size_t)(i0 + mt * 16 + m) * C_ + ks * 32 + q * 8);
  f32x4 x2q[4];
  #pragma unroll
  for (int mt = 0; mt < 4; ++mt) x2q[mt] = *(const f32x4*)(x2B + i0 + mt * 16 + q * 4);

  short8 bfr0[4], bfr1[4];
  auto load_bfr = [&](int tc) {
    const ushort_t* yb0 = ybB + (size_t)tc * 64 * C_;
    #pragma unroll
    for (int nt = 0; nt < 4; ++nt) {
      bfr0[nt] = *(const short8*)(yb0 + (size_t)(nt * 16 + m) * C_ + q * 8);
      bfr1[nt] = *(const short8*)(yb0 + (size_t)(nt * 16 + m) * C_ + 32 + q * 8);
    }
  };
  // Gram tile -> skewed LDS: D[r][c] at row r, slot (c+r)&127 (base-2 scaled bf16)
  auto gram = [&](int tc) {
    const int cb = tc * 64;
    const float* y2j = y2B + cb;
    #pragma unroll
    for (int mt = 0; mt < 4; ++mt) {
      const int r0 = mt * 16 + q * 4;
      #pragma unroll
      for (int nt = 0; nt < 4; ++nt) {
        f32x4 acc = {0.f, 0.f, 0.f, 0.f};
        acc = __builtin_amdgcn_mfma_f32_16x16x32_bf16(af[mt][0], bfr0[nt], acc, 0, 0, 0);
        acc = __builtin_amdgcn_mfma_f32_16x16x32_bf16(af[mt][1], bfr1[nt], acc, 0, 0, 0);
        float y2v = y2j[nt * 16 + m];
        float d0 = fmaf(acc[0], -2.f * INV_LN2, x2q[mt][0] + y2v);
        float d1 = fmaf(acc[1], -2.f * INV_LN2, x2q[mt][1] + y2v);
        float d2 = fmaf(acc[2], -2.f * INV_LN2, x2q[mt][2] + y2v);
        float d3 = fmaf(acc[3], -2.f * INV_LN2, x2q[mt][3] + y2v);
        unsigned p01 = cvt_pk_bf16(d0, d1);
        unsigned p23 = cvt_pk_bf16(d2, d3);
        const int cs = cb + nt * 16 + m + r0;      // col + row for reg 0
        ushort_t* base = Dtw + r0 * DSTR;
        base[             ( cs      & 127)] = (ushort_t)p01;
        base[    DSTR  +  ((cs + 1) & 127)] = (ushort_t)(p01 >> 16);
        base[2 * DSTR  +  ((cs + 2) & 127)] = (ushort_t)p23;
        base[3 * DSTR  +  ((cs + 3) & 127)] = (ushort_t)(p23 >> 16);
      }
    }
  };

  float cur = 0.f, dgp = BIGV;
  const float zsel = (W == 0 && lane == 0) ? 0.f : BIGV;
  const ushort_t* DtwLane = Dtw + lane * DSTR;

  load_bfr(0);
  gram(0);

  #pragma unroll 1
  for (int t = 0; t < 16; ++t) {
    if (t < 15) load_bfr(t + 1);
    float hvv;
    if constexpr (HSRC == 0) {
      hvv = BIGV;
    } else if constexpr (HSRC == 1) {
      spin_lds(cin, t + 1);
      hvv = HbSrc[(t << 6) + lane];
    } else {
      spin_glb(fGin, t + 1);
      hvv = HXin[(t << 6) + lane];
    }
    if (t == 0) dp_chunk<HDST, true >(0, lane, cur, dgp, hvv, zsel, DtwLane, HbDst, HXout);
    else        dp_chunk<HDST, false>(t, lane, cur, dgp, hvv, zsel, DtwLane, HbDst, HXout);
    if constexpr (HDST == 0) {
      if (lane == 0) __hip_atomic_store(cout, t, __ATOMIC_RELEASE, __HIP_MEMORY_SCOPE_WORKGROUP);
    } else if constexpr (HDST == 1) {
      if (lane == 0) __hip_atomic_store(fGout, t, __ATOMIC_RELEASE, __HIP_MEMORY_SCOPE_AGENT);
    }
    if (t < 15) gram(t + 1);
  }
  dp_tail<HDST>(lane, cur, dgp, DtwLane, HbDst, HXout);
  if constexpr (HDST == 0) {
    if (lane == 0) __hip_atomic_store(cout, 16, __ATOMIC_RELEASE, __HIP_MEMORY_SCOPE_WORKGROUP);
  } else if constexpr (HDST == 1) {
    if (lane == 0) __hip_atomic_store(fGout, 16, __ATOMIC_RELEASE, __HIP_MEMORY_SCOPE_AGENT);
  }
  if (W == 15 && lane == 63) *outp = cur * LN2F;
}

__global__ __launch_bounds__(256) void sdtw_kernel(
    const ushort_t* __restrict__ xb, const ushort_t* __restrict__ yb,
    const float* __restrict__ x2g, const float* __restrict__ y2g,
    float* __restrict__ HXg, int* __restrict__ flagsG,
    float* __restrict__ out)
{
  // LDS: Dt 4*64*130*2 = 66560 ; Hb 3*1280*4 = 15360 ; cflag 16  => 81936 B
  // (>80 KiB on purpose: forces 1 block/CU, 1 wave/SIMD, all 256 blocks resident)
  __shared__ ushort_t Dt[4][64 * DSTR];
  __shared__ float Hb[3][HBSTR];
  __shared__ int cflag[4];

  const int b = blockIdx.x & 63;       // blocks b, b+64, b+128, b+192: same XCD slot
  const int sub = blockIdx.x >> 6;     // 0..3 -> bands sub*4 .. sub*4+3
  const int w = threadIdx.x >> 6;
  const int lane = threadIdx.x & 63;
  const int W = sub * 4 + w;

  if (threadIdx.x < 4) cflag[threadIdx.x] = 0;
  __syncthreads();                     // only barrier in the kernel

  const ushort_t* xbB = xb + (size_t)b * L_ * C_;
  const ushort_t* ybB = yb + (size_t)b * L_ * C_;
  const float* x2B = x2g + b * L_;
  const float* y2B = y2g + b * L_;
  // boundary buffers: HXg[b][bnd][1024], bnd = 0,1,2 after bands 3,7,11
  const float* HXin = HXg + ((size_t)b * 3 + (sub - 1)) * L_;
  float* HXout      = HXg + ((size_t)b * 3 + sub) * L_;
  int* fGin  = flagsG + b * 3 + (sub - 1);
  int* fGout = flagsG + b * 3 + sub;
  ushort_t* Dtw = &Dt[w][0];
  const float* HbSrc = (w > 0) ? &Hb[w - 1][0] : &Hb[0][0];
  float* HbDst = (w < 3) ? &Hb[w][0] : &Hb[0][0];
  int* cin  = (w > 0) ? &cflag[w - 1] : &cflag[0];
  int* cout = (w < 3) ? &cflag[w] : &cflag[3];
  float* outp = out + b;

  if (sub == 0) {
    if (w == 0)      run_band<0, 0>(xbB, ybB, x2B, y2B, HXin, HXout, fGin, fGout, Dtw, HbSrc, HbDst, cin, cout, lane, W, outp);
    else if (w < 3)  run_band<1, 0>(xbB, ybB, x2B, y2B, HXin, HXout, fGin, fGout, Dtw, HbSrc, HbDst, cin, cout, lane, W, outp);
    else             run_band<1, 1>(xbB, ybB, x2B, y2B, HXin, HXout, fGin, fGout, Dtw, HbSrc, HbDst, cin, cout, lane, W, outp);
  } else if (sub < 3) {
    if (w == 0)      run_band<2, 0>(xbB, ybB, x2B, y2B, HXin, HXout, fGin, fGout, Dtw, HbSrc, HbDst, cin, cout, lane, W, outp);
    else if (w < 3)  run_band<1, 0>(xbB, ybB, x2B, y2B, HXin, HXout, fGin, fGout, Dtw, HbSrc, HbDst, cin, cout, lane, W, outp);
    else             run_band<1, 1>(xbB, ybB, x2B, y2B, HXin, HXout, fGin, fGout, Dtw, HbSrc, HbDst, cin, cout, lane, W, outp);
  } else {
    if (w == 0)      run_band<2, 0>(xbB, ybB, x2B, y2B, HXin, HXout, fGin, fGout, Dtw, HbSrc, HbDst, cin, cout, lane, W, outp);
    else if (w < 3)  run_band<1, 0>(xbB, ybB, x2B, y2B, HXin, HXout, fGin, fGout, Dtw, HbSrc, HbDst, cin, cout, lane, W, outp);
    else             run_band<1, 2>(xbB, ybB, x2B, y2B, HXin, HXout, fGin, fGout, Dtw, HbSrc, HbDst, cin, cout, lane, W, outp);
  }
}

extern "C" void kernel_launch(void* const* d_in, const int* in_sizes, int n_in,
                              void* d_out, int out_size, void* d_ws, size_t ws_size,
                              hipStream_t stream) {
  const float* x = (const float*)d_in[0];
  const float* y = (const float*)d_in[1];
  float* out = (float*)d_out;

  // ws: xb 8MB | yb 8MB | x2 256KB | y2 256KB | HX 768KB | flagsG 768B
  char* ws = (char*)d_ws;
  const size_t XB = (size_t)B_ * L_ * C_ * 2;
  const size_t NB = (size_t)B_ * L_ * 4;
  ushort_t* xb = (ushort_t*)ws;
  ushort_t* yb = (ushort_t*)(ws + XB);
  float* x2 = (float*)(ws + 2 * XB);
  float* y2 = (float*)(ws + 2 * XB + NB);
  float* HX = (float*)(ws + 2 * XB + 2 * NB);
  int* flagsG = (int*)(ws + 2 * XB + 2 * NB + (size_t)B_ * 3 * L_ * 4);

  prep_kernel<<<512, 256, 0, stream>>>(x, y, xb, yb, x2, y2, flagsG);
  sdtw_kernel<<<256, 256, 0, stream>>>(xb, yb, x2, y2, HX, flagsG, out);
}